// Round 3
// baseline (405.456 us; speedup 1.0000x reference)
//
#include <hip/hip_runtime.h>
#include <math.h>

#define N_NODES 50000
#define K_DIM 128
#define CAP 64   // padded-CSR capacity; in-degree is Poisson(16), P(>=64) ~ e^-40

// ---------------- graph build (single fused pass) ----------------

// outd[src]++ ; p = cursor[dst]++ ; csr[dst*CAP + p] = src
// cursor doubles as the in-degree array.
__global__ void build_kernel(const int* __restrict__ src, const int* __restrict__ dst,
                             int E, int* __restrict__ outd, int* __restrict__ cursor,
                             int* __restrict__ csr) {
    int i = blockIdx.x * blockDim.x + threadIdx.x;
    if (i < E) {
        int s = src[i];
        int v = dst[i];
        atomicAdd(&outd[s], 1);
        int p = atomicAdd(&cursor[v], 1);
        if (p < CAP) csr[v * CAP + p] = s;   // clamp: never triggers on sane data
    }
}

__global__ void norm_kernel(const int* __restrict__ outd, const int* __restrict__ ind,
                            float* __restrict__ nsrc, float* __restrict__ ndst, int n) {
    int i = blockIdx.x * blockDim.x + threadIdx.x;
    if (i < n) {
        int od = outd[i]; if (od < 1) od = 1;
        int id = ind[i];  if (id < 1) id = 1;
        nsrc[i] = 1.0f / sqrtf((float)od);
        ndst[i] = 1.0f / sqrtf((float)id);
    }
}

// ---------------- per-layer compute ----------------

// Y[r][c] = nsrc[r] * sum_k X[r][k] * W[k][c]   (K = 128 fixed)
// BM=128, BK=32, 8x8 microtile. Xs transposed [BK][BM+4] so A-frag reads are
// ds_read_b128 (16B-aligned via +4 pad; bank-conflict-free per arithmetic).
template <int M>
__global__ __launch_bounds__(256) void gemm_scale_kernel(const float* __restrict__ X,
                                                         const float* __restrict__ W,
                                                         const float* __restrict__ nsrc,
                                                         float* __restrict__ Y, int n) {
    constexpr int BM = 128, BK = 32, K = K_DIM;
    constexpr int CGRPS = M / 8;            // 16 for M=128, 8 for M=64
    constexpr int THREADS = CGRPS * 16;     // 256 / 128
    __shared__ float Xs[BK][BM + 4];
    __shared__ float Ws[BK][M];
    int tid = threadIdx.x;
    int rowBlock = blockIdx.x * BM;
    int c0 = (tid % CGRPS) * 8;
    int r0 = (tid / CGRPS) * 8;
    float acc[8][8] = {};
    for (int k0 = 0; k0 < K; k0 += BK) {
        constexpr int XL = (BM * BK) / (THREADS * 4);
        #pragma unroll
        for (int l = 0; l < XL; ++l) {
            int idx = (tid + l * THREADS) * 4;
            int r = idx / BK;
            int kk = idx % BK;
            int gr = rowBlock + r;
            float4 v = make_float4(0.f, 0.f, 0.f, 0.f);
            if (gr < n) v = *(const float4*)&X[(size_t)gr * K + k0 + kk];
            Xs[kk + 0][r] = v.x; Xs[kk + 1][r] = v.y;
            Xs[kk + 2][r] = v.z; Xs[kk + 3][r] = v.w;
        }
        constexpr int WL = (BK * M) / (THREADS * 4);
        #pragma unroll
        for (int l = 0; l < WL; ++l) {
            int idx = (tid + l * THREADS) * 4;
            int kk = idx / M;
            int cc = idx % M;
            *(float4*)&Ws[kk][cc] = *(const float4*)&W[(size_t)(k0 + kk) * M + cc];
        }
        __syncthreads();
        #pragma unroll
        for (int kk = 0; kk < BK; ++kk) {
            float4 a0 = *(const float4*)&Xs[kk][r0];
            float4 a1 = *(const float4*)&Xs[kk][r0 + 4];
            float4 b0 = *(const float4*)&Ws[kk][c0];
            float4 b1 = *(const float4*)&Ws[kk][c0 + 4];
            float av[8] = {a0.x, a0.y, a0.z, a0.w, a1.x, a1.y, a1.z, a1.w};
            float bv[8] = {b0.x, b0.y, b0.z, b0.w, b1.x, b1.y, b1.z, b1.w};
            #pragma unroll
            for (int ii = 0; ii < 8; ++ii)
                #pragma unroll
                for (int jj = 0; jj < 8; ++jj)
                    acc[ii][jj] = fmaf(av[ii], bv[jj], acc[ii][jj]);
        }
        __syncthreads();
    }
    #pragma unroll
    for (int ii = 0; ii < 8; ++ii) {
        int r = rowBlock + r0 + ii;
        if (r < n) {
            float s = nsrc[r];
            float4 o0, o1;
            o0.x = acc[ii][0] * s; o0.y = acc[ii][1] * s;
            o0.z = acc[ii][2] * s; o0.w = acc[ii][3] * s;
            o1.x = acc[ii][4] * s; o1.y = acc[ii][5] * s;
            o1.z = acc[ii][6] * s; o1.w = acc[ii][7] * s;
            *(float4*)&Y[(size_t)r * M + c0]     = o0;
            *(float4*)&Y[(size_t)r * M + c0 + 4] = o1;
        }
    }
}

// Z[v][f] = act( ndst[v] * sum_{s in padded-CSR[v]} Y[s][f] + bias[f] )
// Indices loaded as int4 (4 independent gathers per index load); tail slots
// clamped to dummy row N_NODES which the host pre-zeroes (branch-free tail).
template <int M, bool RELU>
__global__ __launch_bounds__(256) void agg_kernel(const float* __restrict__ Y,
                                                  const int* __restrict__ indeg,
                                                  const int* __restrict__ csr,
                                                  const float* __restrict__ ndst,
                                                  const float* __restrict__ bias,
                                                  float* __restrict__ Z, int n) {
    constexpr int LPN = M / 4;        // lanes per node
    constexpr int NPB = 256 / LPN;    // nodes per block
    int v = blockIdx.x * NPB + threadIdx.x / LPN;
    if (v >= n) return;
    int f4 = (threadIdx.x % LPN) * 4;
    int deg = indeg[v]; if (deg > CAP) deg = CAP;
    const int* __restrict__ row = &csr[(size_t)v * CAP];
    float4 acc = make_float4(0.f, 0.f, 0.f, 0.f);
    for (int i = 0; i < deg; i += 4) {
        int4 ss = *(const int4*)&row[i];
        int s0 = ss.x;
        int s1 = (i + 1 < deg) ? ss.y : N_NODES;
        int s2 = (i + 2 < deg) ? ss.z : N_NODES;
        int s3 = (i + 3 < deg) ? ss.w : N_NODES;
        float4 a = *(const float4*)&Y[(size_t)s0 * M + f4];
        float4 b = *(const float4*)&Y[(size_t)s1 * M + f4];
        float4 c = *(const float4*)&Y[(size_t)s2 * M + f4];
        float4 d = *(const float4*)&Y[(size_t)s3 * M + f4];
        acc.x += (a.x + b.x) + (c.x + d.x);
        acc.y += (a.y + b.y) + (c.y + d.y);
        acc.z += (a.z + b.z) + (c.z + d.z);
        acc.w += (a.w + b.w) + (c.w + d.w);
    }
    float nd = ndst[v];
    float4 bb = *(const float4*)&bias[f4];
    float4 o;
    o.x = nd * acc.x + bb.x; o.y = nd * acc.y + bb.y;
    o.z = nd * acc.z + bb.z; o.w = nd * acc.w + bb.w;
    if (RELU) {
        o.x = fmaxf(o.x, 0.f); o.y = fmaxf(o.y, 0.f);
        o.z = fmaxf(o.z, 0.f); o.w = fmaxf(o.w, 0.f);
    }
    *(float4*)&Z[(size_t)v * M + f4] = o;
}

// ---------------- launch ----------------

extern "C" void kernel_launch(void* const* d_in, const int* in_sizes, int n_in,
                              void* d_out, int out_size, void* d_ws, size_t ws_size,
                              hipStream_t stream) {
    const float* features = (const float*)d_in[0];
    const float* W1 = (const float*)d_in[1];
    const float* b1 = (const float*)d_in[2];
    const float* W2 = (const float*)d_in[3];
    const float* b2 = (const float*)d_in[4];
    const float* W3 = (const float*)d_in[5];
    const float* b3 = (const float*)d_in[6];
    const int* src = (const int*)d_in[7];
    const int* dst = (const int*)d_in[8];
    const int E = in_sizes[7];
    const int N = N_NODES;

    char* w = (char*)d_ws;
    auto alloc = [&](size_t bytes) {
        char* p = w;
        w += (bytes + 255) & ~(size_t)255;
        return p;
    };
    // bufA holds GEMM outputs (gather sources): (N+1) rows, dummy row N zeroed.
    float* bufA   = (float*)alloc((size_t)(N + 1) * 128 * 4);
    float* bufB   = (float*)alloc((size_t)N * 128 * 4);
    int*   outd   = (int*)alloc((size_t)N * 4);
    int*   cursor = (int*)alloc((size_t)N * 4);   // becomes in-degree
    float* nsrc   = (float*)alloc((size_t)N * 4);
    float* ndst   = (float*)alloc((size_t)N * 4);
    int*   csr    = (int*)alloc((size_t)N * CAP * 4);

    hipMemsetAsync(outd, 0, (size_t)N * 4, stream);
    hipMemsetAsync(cursor, 0, (size_t)N * 4, stream);
    hipMemsetAsync(bufA + (size_t)N * 128, 0, 128 * 4, stream);  // dummy row (M=128)

    build_kernel<<<(E + 255) / 256, 256, 0, stream>>>(src, dst, E, outd, cursor, csr);
    norm_kernel<<<(N + 255) / 256, 256, 0, stream>>>(outd, cursor, nsrc, ndst, N);

    int gblocks = (N + 127) / 128;
    // Layer 1: Y = D_src * (X @ W1); Z = relu(D_dst * S Y + b1)
    gemm_scale_kernel<128><<<gblocks, 256, 0, stream>>>(features, W1, nsrc, bufA, N);
    agg_kernel<128, true><<<(N + 7) / 8, 256, 0, stream>>>(bufA, cursor, csr, ndst, b1, bufB, N);
    // Layer 2
    gemm_scale_kernel<128><<<gblocks, 256, 0, stream>>>(bufB, W2, nsrc, bufA, N);
    agg_kernel<128, true><<<(N + 7) / 8, 256, 0, stream>>>(bufA, cursor, csr, ndst, b2, bufB, N);
    // Layer 3 (no relu): GEMM to 64-d; dummy row for 64-wide layout sits inside
    // the old 128-wide data, so re-zero it first.
    hipMemsetAsync(bufA + (size_t)N * 64, 0, 64 * 4, stream);
    gemm_scale_kernel<64><<<gblocks, 128, 0, stream>>>(bufB, W3, nsrc, bufA, N);
    agg_kernel<64, false><<<(N + 15) / 16, 256, 0, stream>>>(bufA, cursor, csr, ndst, b3, (float*)d_out, N);
}

// Round 4
// 399.011 us; speedup vs baseline: 1.0162x; 1.0162x over previous
//
#include <hip/hip_runtime.h>
#include <math.h>

#define N_NODES 50000
#define K_DIM 128
#define CAP 64   // padded-CSR capacity; in-degree is Poisson(16), P(>=64) ~ e^-40

typedef __attribute__((ext_vector_type(8))) short short8_t;   // 8 bf16 (4 VGPRs)
typedef __attribute__((ext_vector_type(4))) float f32x4_t;    // MFMA acc

__device__ inline unsigned short f2bf(float x) {   // round-to-nearest-even
    unsigned u = __float_as_uint(x);
    unsigned r = u + 0x7fffu + ((u >> 16) & 1u);
    return (unsigned short)(r >> 16);
}
__device__ inline float bf2f(unsigned short h) {
    return __uint_as_float(((unsigned)h) << 16);
}

// ---------------- graph build (single fused pass) ----------------

__global__ void build_kernel(const int* __restrict__ src, const int* __restrict__ dst,
                             int E, int* __restrict__ outd, int* __restrict__ cursor,
                             int* __restrict__ csr) {
    int i = blockIdx.x * blockDim.x + threadIdx.x;
    if (i < E) {
        int s = src[i];
        int v = dst[i];
        atomicAdd(&outd[s], 1);
        int p = atomicAdd(&cursor[v], 1);
        if (p < CAP) csr[v * CAP + p] = s;
    }
}

__global__ void norm_kernel(const int* __restrict__ outd, const int* __restrict__ ind,
                            float* __restrict__ nsrc, float* __restrict__ ndst, int n) {
    int i = blockIdx.x * blockDim.x + threadIdx.x;
    if (i < n) {
        int od = outd[i]; if (od < 1) od = 1;
        int id = ind[i];  if (id < 1) id = 1;
        nsrc[i] = 1.0f / sqrtf((float)od);
        ndst[i] = 1.0f / sqrtf((float)id);
    }
}

// ---------------- W split+transpose: W[K][M] fp32 -> Wt_hi/lo[M][K] bf16 ----

__global__ void split_w_kernel(const float* __restrict__ W,
                               unsigned short* __restrict__ Wt_hi,
                               unsigned short* __restrict__ Wt_lo, int M) {
    int i = blockIdx.x * blockDim.x + threadIdx.x;  // over K_DIM*M
    if (i < K_DIM * M) {
        int k = i / M, nn = i % M;
        float w = W[i];
        unsigned short hi = f2bf(w);
        unsigned short lo = f2bf(w - bf2f(hi));
        Wt_hi[nn * K_DIM + k] = hi;
        Wt_lo[nn * K_DIM + k] = lo;
    }
}

// ---------------- split-bf16 MFMA GEMM ----------------
// Y[r][c] = nsrc[r] * sum_k X[r][k]*W[k][c], K=128.
// X fp32 staged to LDS as bf16 hi/lo; W pre-split+transposed (Wt[n][k]).
// Block: 256 thr = 4 waves, 64 rows; wave w owns rows w*16..w*16+15.
// mfma_f32_16x16x32_bf16: A[m=lane&15][k=(lane>>4)*8+j]; B[k][n=lane&15];
// D: col=lane&15, row=(lane>>4)*4+reg.
template <int M>
__global__ __launch_bounds__(256) void gemm_mfma_kernel(
        const float* __restrict__ X,
        const unsigned short* __restrict__ Wt_hi,
        const unsigned short* __restrict__ Wt_lo,
        const float* __restrict__ nsrc, float* __restrict__ Y, int n) {
    constexpr int LSTR = 136;   // bf16 row stride: 272B = 17*16B -> 2-way bank alias only
    __shared__ short Xhi[64 * LSTR];
    __shared__ short Xlo[64 * LSTR];
    int tid = threadIdx.x;
    int lane = tid & 63, wave = tid >> 6;
    int rowBlock = blockIdx.x * 64;

    // stage 64x128 fp32 -> bf16 hi/lo in LDS
    #pragma unroll
    for (int l = 0; l < 8; ++l) {
        int idx = (tid + l * 256) * 4;         // 0..8188
        int r = idx >> 7;                      // /128
        int c = idx & 127;
        float4 v = make_float4(0.f, 0.f, 0.f, 0.f);
        int gr = rowBlock + r;
        if (gr < n) v = *(const float4*)&X[(size_t)gr * K_DIM + c];
        unsigned short h0 = f2bf(v.x), h1 = f2bf(v.y), h2 = f2bf(v.z), h3 = f2bf(v.w);
        short4 hs = {(short)h0, (short)h1, (short)h2, (short)h3};
        short4 ls = {(short)f2bf(v.x - bf2f(h0)), (short)f2bf(v.y - bf2f(h1)),
                     (short)f2bf(v.z - bf2f(h2)), (short)f2bf(v.w - bf2f(h3))};
        *(short4*)&Xhi[r * LSTR + c] = hs;
        *(short4*)&Xlo[r * LSTR + c] = ls;
    }
    __syncthreads();

    int m = lane & 15, q = lane >> 4;
    // A fragments (regs, reused across all col tiles): 4 k-chunks x (hi,lo)
    short8_t ah[4], al[4];
    {
        int abase = (wave * 16 + m) * LSTR + q * 8;
        #pragma unroll
        for (int kc = 0; kc < 4; ++kc) {
            ah[kc] = *(const short8_t*)&Xhi[abase + kc * 32];
            al[kc] = *(const short8_t*)&Xlo[abase + kc * 32];
        }
    }
    // nsrc for this lane's 4 output rows
    float ns[4];
    int orow0 = rowBlock + wave * 16 + q * 4;
    #pragma unroll
    for (int r = 0; r < 4; ++r) ns[r] = (orow0 + r < n) ? nsrc[orow0 + r] : 0.f;

    constexpr int CT = M / 16;
    #pragma unroll
    for (int c = 0; c < CT; ++c) {
        const unsigned short* bh_p = Wt_hi + (size_t)(c * 16 + m) * K_DIM + q * 8;
        const unsigned short* bl_p = Wt_lo + (size_t)(c * 16 + m) * K_DIM + q * 8;
        short8_t bh[4], bl[4];
        #pragma unroll
        for (int kc = 0; kc < 4; ++kc) {
            bh[kc] = *(const short8_t*)(bh_p + kc * 32);
            bl[kc] = *(const short8_t*)(bl_p + kc * 32);
        }
        f32x4_t acc = {0.f, 0.f, 0.f, 0.f};
        #pragma unroll
        for (int kc = 0; kc < 4; ++kc) {
            acc = __builtin_amdgcn_mfma_f32_16x16x32_bf16(ah[kc], bh[kc], acc, 0, 0, 0);
            acc = __builtin_amdgcn_mfma_f32_16x16x32_bf16(ah[kc], bl[kc], acc, 0, 0, 0);
            acc = __builtin_amdgcn_mfma_f32_16x16x32_bf16(al[kc], bh[kc], acc, 0, 0, 0);
        }
        int col = c * 16 + m;
        #pragma unroll
        for (int r = 0; r < 4; ++r) {
            int row = orow0 + r;
            if (row < n) Y[(size_t)row * M + col] = acc[r] * ns[r];
        }
    }
}

// ---------------- aggregation ----------------
// Z[v][f] = act( ndst[v] * sum_{s in padded-CSR[v]} Y[s][f] + bias[f] )
template <int M, bool RELU>
__global__ __launch_bounds__(256) void agg_kernel(const float* __restrict__ Y,
                                                  const int* __restrict__ indeg,
                                                  const int* __restrict__ csr,
                                                  const float* __restrict__ ndst,
                                                  const float* __restrict__ bias,
                                                  float* __restrict__ Z, int n) {
    constexpr int LPN = M / 4;
    constexpr int NPB = 256 / LPN;
    int v = blockIdx.x * NPB + threadIdx.x / LPN;
    if (v >= n) return;
    int f4 = (threadIdx.x % LPN) * 4;
    int deg = indeg[v]; if (deg > CAP) deg = CAP;
    const int* __restrict__ row = &csr[(size_t)v * CAP];
    float4 acc = make_float4(0.f, 0.f, 0.f, 0.f);
    for (int i = 0; i < deg; i += 4) {
        int4 ss = *(const int4*)&row[i];
        int s0 = ss.x;
        int s1 = (i + 1 < deg) ? ss.y : N_NODES;
        int s2 = (i + 2 < deg) ? ss.z : N_NODES;
        int s3 = (i + 3 < deg) ? ss.w : N_NODES;
        float4 a = *(const float4*)&Y[(size_t)s0 * M + f4];
        float4 b = *(const float4*)&Y[(size_t)s1 * M + f4];
        float4 c = *(const float4*)&Y[(size_t)s2 * M + f4];
        float4 d = *(const float4*)&Y[(size_t)s3 * M + f4];
        acc.x += (a.x + b.x) + (c.x + d.x);
        acc.y += (a.y + b.y) + (c.y + d.y);
        acc.z += (a.z + b.z) + (c.z + d.z);
        acc.w += (a.w + b.w) + (c.w + d.w);
    }
    float nd = ndst[v];
    float4 bb = *(const float4*)&bias[f4];
    float4 o;
    o.x = nd * acc.x + bb.x; o.y = nd * acc.y + bb.y;
    o.z = nd * acc.z + bb.z; o.w = nd * acc.w + bb.w;
    if (RELU) {
        o.x = fmaxf(o.x, 0.f); o.y = fmaxf(o.y, 0.f);
        o.z = fmaxf(o.z, 0.f); o.w = fmaxf(o.w, 0.f);
    }
    *(float4*)&Z[(size_t)v * M + f4] = o;
}

// ---------------- launch ----------------

extern "C" void kernel_launch(void* const* d_in, const int* in_sizes, int n_in,
                              void* d_out, int out_size, void* d_ws, size_t ws_size,
                              hipStream_t stream) {
    const float* features = (const float*)d_in[0];
    const float* W1 = (const float*)d_in[1];
    const float* b1 = (const float*)d_in[2];
    const float* W2 = (const float*)d_in[3];
    const float* b2 = (const float*)d_in[4];
    const float* W3 = (const float*)d_in[5];
    const float* b3 = (const float*)d_in[6];
    const int* src = (const int*)d_in[7];
    const int* dst = (const int*)d_in[8];
    const int E = in_sizes[7];
    const int N = N_NODES;

    char* w = (char*)d_ws;
    auto alloc = [&](size_t bytes) {
        char* p = w;
        w += (bytes + 255) & ~(size_t)255;
        return p;
    };
    float* bufA   = (float*)alloc((size_t)(N + 1) * 128 * 4);  // +dummy row N (zeros)
    float* bufB   = (float*)alloc((size_t)N * 128 * 4);
    int*   outd   = (int*)alloc((size_t)N * 4);
    int*   cursor = (int*)alloc((size_t)N * 4);   // becomes in-degree
    float* nsrc   = (float*)alloc((size_t)N * 4);
    float* ndst   = (float*)alloc((size_t)N * 4);
    int*   csr    = (int*)alloc((size_t)N * CAP * 4);
    unsigned short* W1h = (unsigned short*)alloc(128 * 128 * 2);
    unsigned short* W1l = (unsigned short*)alloc(128 * 128 * 2);
    unsigned short* W2h = (unsigned short*)alloc(128 * 128 * 2);
    unsigned short* W2l = (unsigned short*)alloc(128 * 128 * 2);
    unsigned short* W3h = (unsigned short*)alloc(64 * 128 * 2);
    unsigned short* W3l = (unsigned short*)alloc(64 * 128 * 2);

    hipMemsetAsync(outd, 0, (size_t)N * 4, stream);
    hipMemsetAsync(cursor, 0, (size_t)N * 4, stream);
    hipMemsetAsync(bufA + (size_t)N * 128, 0, 128 * 4, stream);  // dummy row (M=128)

    build_kernel<<<(E + 255) / 256, 256, 0, stream>>>(src, dst, E, outd, cursor, csr);
    norm_kernel<<<(N + 255) / 256, 256, 0, stream>>>(outd, cursor, nsrc, ndst, N);
    split_w_kernel<<<64, 256, 0, stream>>>(W1, W1h, W1l, 128);
    split_w_kernel<<<64, 256, 0, stream>>>(W2, W2h, W2l, 128);
    split_w_kernel<<<32, 256, 0, stream>>>(W3, W3h, W3l, 64);

    int gblocks = (N + 63) / 64;
    // Layer 1
    gemm_mfma_kernel<128><<<gblocks, 256, 0, stream>>>(features, W1h, W1l, nsrc, bufA, N);
    agg_kernel<128, true><<<(N + 7) / 8, 256, 0, stream>>>(bufA, cursor, csr, ndst, b1, bufB, N);
    // Layer 2
    gemm_mfma_kernel<128><<<gblocks, 256, 0, stream>>>(bufB, W2h, W2l, nsrc, bufA, N);
    agg_kernel<128, true><<<(N + 7) / 8, 256, 0, stream>>>(bufA, cursor, csr, ndst, b2, bufB, N);
    // Layer 3 (no relu): re-zero dummy row for 64-wide layout, then into d_out
    hipMemsetAsync(bufA + (size_t)N * 64, 0, 64 * 4, stream);
    gemm_mfma_kernel<64><<<gblocks, 256, 0, stream>>>(bufB, W3h, W3l, nsrc, bufA, N);
    agg_kernel<64, false><<<(N + 15) / 16, 256, 0, stream>>>(bufA, cursor, csr, ndst, b3, (float*)d_out, N);
}

// Round 5
// 348.551 us; speedup vs baseline: 1.1633x; 1.1448x over previous
//
#include <hip/hip_runtime.h>
#include <math.h>

#define N_NODES 50000
#define K_DIM 128
#define CAP 64   // padded-CSR capacity; in-degree is Poisson(16), P(>=64) ~ e^-40

typedef __attribute__((ext_vector_type(8))) short short8_t;   // 8 bf16 (4 VGPRs)
typedef __attribute__((ext_vector_type(4))) float f32x4_t;    // MFMA acc

__device__ inline unsigned short f2bf(float x) {   // round-to-nearest-even
    unsigned u = __float_as_uint(x);
    unsigned r = u + 0x7fffu + ((u >> 16) & 1u);
    return (unsigned short)(r >> 16);
}
__device__ inline float bf2f(unsigned short h) {
    return __uint_as_float(((unsigned)h) << 16);
}

// ---------------- graph build (single fused pass) ----------------

__global__ void build_kernel(const int* __restrict__ src, const int* __restrict__ dst,
                             int E, int* __restrict__ outd, int* __restrict__ cursor,
                             int* __restrict__ csr) {
    int i = blockIdx.x * blockDim.x + threadIdx.x;
    if (i < E) {
        int s = src[i];
        int v = dst[i];
        atomicAdd(&outd[s], 1);
        int p = atomicAdd(&cursor[v], 1);
        if (p < CAP) csr[v * CAP + p] = s;
    }
}

__global__ void norm_kernel(const int* __restrict__ outd, const int* __restrict__ ind,
                            float* __restrict__ nsrc, float* __restrict__ ndst, int n) {
    int i = blockIdx.x * blockDim.x + threadIdx.x;
    if (i < n) {
        int od = outd[i]; if (od < 1) od = 1;
        int id = ind[i];  if (id < 1) id = 1;
        nsrc[i] = 1.0f / sqrtf((float)od);
        ndst[i] = 1.0f / sqrtf((float)id);
    }
}

// ---------------- W split into MFMA B-fragment-major tables ----------------
// WB[tile c][kc][lane][j=0..7]: value = W[k][n], k = kc*32 + (lane>>4)*8 + j,
// n = c*16 + (lane&15).  In the GEMM, lane loads the contiguous 16B at
// ((c*4+kc)*64 + lane)*8 -> wave reads one contiguous 1KB block (coalesced).
__global__ void split_w_frag_kernel(const float* __restrict__ W,
                                    unsigned short* __restrict__ WBh,
                                    unsigned short* __restrict__ WBl, int M) {
    int i = blockIdx.x * blockDim.x + threadIdx.x;   // over (M/16)*4*64
    int total = (M / 16) * 4 * 64;
    if (i >= total) return;
    int c    = i >> 8;          // /256
    int rem  = i & 255;
    int kc   = rem >> 6;
    int lane = rem & 63;
    int m = lane & 15, q = lane >> 4;
    int n = c * 16 + m;
    #pragma unroll
    for (int j = 0; j < 8; ++j) {
        int k = kc * 32 + q * 8 + j;
        float w = W[(size_t)k * M + n];
        unsigned short hi = f2bf(w);
        unsigned short lo = f2bf(w - bf2f(hi));
        WBh[(size_t)i * 8 + j] = hi;
        WBl[(size_t)i * 8 + j] = lo;
    }
}

// ---------------- split-bf16 MFMA GEMM ----------------
// Y[r][c] = nsrc[r] * sum_k X[r][k]*W[k][c], K=128.
// X fp32 staged to LDS as bf16 hi/lo; W pre-split in fragment-major order.
// Block: 256 thr = 4 waves, 64 rows; wave w owns rows w*16..w*16+15.
template <int M>
__global__ __launch_bounds__(256) void gemm_mfma_kernel(
        const float* __restrict__ X,
        const unsigned short* __restrict__ WBh_,
        const unsigned short* __restrict__ WBl_,
        const float* __restrict__ nsrc, float* __restrict__ Y, int n) {
    constexpr int LSTR = 136;   // bf16 row stride: 272B -> 2-way bank alias only (free)
    __shared__ short Xhi[64 * LSTR];
    __shared__ short Xlo[64 * LSTR];
    int tid = threadIdx.x;
    int lane = tid & 63, wave = tid >> 6;
    int rowBlock = blockIdx.x * 64;

    // stage 64x128 fp32 -> bf16 hi/lo in LDS
    #pragma unroll
    for (int l = 0; l < 8; ++l) {
        int idx = (tid + l * 256) * 4;         // 0..8188
        int r = idx >> 7;                      // /128
        int c = idx & 127;
        float4 v = make_float4(0.f, 0.f, 0.f, 0.f);
        int gr = rowBlock + r;
        if (gr < n) v = *(const float4*)&X[(size_t)gr * K_DIM + c];
        unsigned short h0 = f2bf(v.x), h1 = f2bf(v.y), h2 = f2bf(v.z), h3 = f2bf(v.w);
        short4 hs = {(short)h0, (short)h1, (short)h2, (short)h3};
        short4 ls = {(short)f2bf(v.x - bf2f(h0)), (short)f2bf(v.y - bf2f(h1)),
                     (short)f2bf(v.z - bf2f(h2)), (short)f2bf(v.w - bf2f(h3))};
        *(short4*)&Xhi[r * LSTR + c] = hs;
        *(short4*)&Xlo[r * LSTR + c] = ls;
    }
    __syncthreads();

    int m = lane & 15, q = lane >> 4;
    // A fragments (regs, reused across all col tiles): 4 k-chunks x (hi,lo)
    short8_t ah[4], al[4];
    {
        int abase = (wave * 16 + m) * LSTR + q * 8;
        #pragma unroll
        for (int kc = 0; kc < 4; ++kc) {
            ah[kc] = *(const short8_t*)&Xhi[abase + kc * 32];
            al[kc] = *(const short8_t*)&Xlo[abase + kc * 32];
        }
    }
    // nsrc for this lane's 4 output rows
    float ns[4];
    int orow0 = rowBlock + wave * 16 + q * 4;
    #pragma unroll
    for (int r = 0; r < 4; ++r) ns[r] = (orow0 + r < n) ? nsrc[orow0 + r] : 0.f;

    const short8_t* WBh = (const short8_t*)WBh_;
    const short8_t* WBl = (const short8_t*)WBl_;
    constexpr int CT = M / 16;
    #pragma unroll
    for (int c = 0; c < CT; ++c) {
        short8_t bh[4], bl[4];
        #pragma unroll
        for (int kc = 0; kc < 4; ++kc) {
            bh[kc] = WBh[(c * 4 + kc) * 64 + lane];   // contiguous 1KB per wave
            bl[kc] = WBl[(c * 4 + kc) * 64 + lane];
        }
        f32x4_t acc = {0.f, 0.f, 0.f, 0.f};
        #pragma unroll
        for (int kc = 0; kc < 4; ++kc) {
            acc = __builtin_amdgcn_mfma_f32_16x16x32_bf16(ah[kc], bh[kc], acc, 0, 0, 0);
            acc = __builtin_amdgcn_mfma_f32_16x16x32_bf16(ah[kc], bl[kc], acc, 0, 0, 0);
            acc = __builtin_amdgcn_mfma_f32_16x16x32_bf16(al[kc], bh[kc], acc, 0, 0, 0);
        }
        int col = c * 16 + m;
        #pragma unroll
        for (int r = 0; r < 4; ++r) {
            int row = orow0 + r;
            if (row < n) Y[(size_t)row * M + col] = acc[r] * ns[r];
        }
    }
}

// ---------------- aggregation ----------------
// Z[v][f] = act( ndst[v] * sum_{s in padded-CSR[v]} Y[s][f] + bias[f] )
template <int M, bool RELU>
__global__ __launch_bounds__(256) void agg_kernel(const float* __restrict__ Y,
                                                  const int* __restrict__ indeg,
                                                  const int* __restrict__ csr,
                                                  const float* __restrict__ ndst,
                                                  const float* __restrict__ bias,
                                                  float* __restrict__ Z, int n) {
    constexpr int LPN = M / 4;
    constexpr int NPB = 256 / LPN;
    int v = blockIdx.x * NPB + threadIdx.x / LPN;
    if (v >= n) return;
    int f4 = (threadIdx.x % LPN) * 4;
    int deg = indeg[v]; if (deg > CAP) deg = CAP;
    const int* __restrict__ row = &csr[(size_t)v * CAP];
    float4 acc = make_float4(0.f, 0.f, 0.f, 0.f);
    for (int i = 0; i < deg; i += 4) {
        int4 ss = *(const int4*)&row[i];
        int s0 = ss.x;
        int s1 = (i + 1 < deg) ? ss.y : N_NODES;
        int s2 = (i + 2 < deg) ? ss.z : N_NODES;
        int s3 = (i + 3 < deg) ? ss.w : N_NODES;
        float4 a = *(const float4*)&Y[(size_t)s0 * M + f4];
        float4 b = *(const float4*)&Y[(size_t)s1 * M + f4];
        float4 c = *(const float4*)&Y[(size_t)s2 * M + f4];
        float4 d = *(const float4*)&Y[(size_t)s3 * M + f4];
        acc.x += (a.x + b.x) + (c.x + d.x);
        acc.y += (a.y + b.y) + (c.y + d.y);
        acc.z += (a.z + b.z) + (c.z + d.z);
        acc.w += (a.w + b.w) + (c.w + d.w);
    }
    float nd = ndst[v];
    float4 bb = *(const float4*)&bias[f4];
    float4 o;
    o.x = nd * acc.x + bb.x; o.y = nd * acc.y + bb.y;
    o.z = nd * acc.z + bb.z; o.w = nd * acc.w + bb.w;
    if (RELU) {
        o.x = fmaxf(o.x, 0.f); o.y = fmaxf(o.y, 0.f);
        o.z = fmaxf(o.z, 0.f); o.w = fmaxf(o.w, 0.f);
    }
    *(float4*)&Z[(size_t)v * M + f4] = o;
}

// ---------------- launch ----------------

extern "C" void kernel_launch(void* const* d_in, const int* in_sizes, int n_in,
                              void* d_out, int out_size, void* d_ws, size_t ws_size,
                              hipStream_t stream) {
    const float* features = (const float*)d_in[0];
    const float* W1 = (const float*)d_in[1];
    const float* b1 = (const float*)d_in[2];
    const float* W2 = (const float*)d_in[3];
    const float* b2 = (const float*)d_in[4];
    const float* W3 = (const float*)d_in[5];
    const float* b3 = (const float*)d_in[6];
    const int* src = (const int*)d_in[7];
    const int* dst = (const int*)d_in[8];
    const int E = in_sizes[7];
    const int N = N_NODES;

    char* w = (char*)d_ws;
    auto alloc = [&](size_t bytes) {
        char* p = w;
        w += (bytes + 255) & ~(size_t)255;
        return p;
    };
    float* bufA   = (float*)alloc((size_t)(N + 1) * 128 * 4);  // +dummy row N (zeros)
    float* bufB   = (float*)alloc((size_t)N * 128 * 4);
    int*   outd   = (int*)alloc((size_t)N * 4);
    int*   cursor = (int*)alloc((size_t)N * 4);   // becomes in-degree
    float* nsrc   = (float*)alloc((size_t)N * 4);
    float* ndst   = (float*)alloc((size_t)N * 4);
    int*   csr    = (int*)alloc((size_t)N * CAP * 4);
    unsigned short* W1h = (unsigned short*)alloc(128 * 128 * 2);
    unsigned short* W1l = (unsigned short*)alloc(128 * 128 * 2);
    unsigned short* W2h = (unsigned short*)alloc(128 * 128 * 2);
    unsigned short* W2l = (unsigned short*)alloc(128 * 128 * 2);
    unsigned short* W3h = (unsigned short*)alloc(64 * 128 * 2);
    unsigned short* W3l = (unsigned short*)alloc(64 * 128 * 2);

    hipMemsetAsync(outd, 0, (size_t)N * 4, stream);
    hipMemsetAsync(cursor, 0, (size_t)N * 4, stream);
    hipMemsetAsync(bufA + (size_t)N * 128, 0, 128 * 4, stream);  // dummy row (M=128)

    build_kernel<<<(E + 255) / 256, 256, 0, stream>>>(src, dst, E, outd, cursor, csr);
    norm_kernel<<<(N + 255) / 256, 256, 0, stream>>>(outd, cursor, nsrc, ndst, N);
    split_w_frag_kernel<<<8, 256, 0, stream>>>(W1, W1h, W1l, 128);
    split_w_frag_kernel<<<8, 256, 0, stream>>>(W2, W2h, W2l, 128);
    split_w_frag_kernel<<<4, 256, 0, stream>>>(W3, W3h, W3l, 64);

    int gblocks = (N + 63) / 64;
    // Layer 1
    gemm_mfma_kernel<128><<<gblocks, 256, 0, stream>>>(features, W1h, W1l, nsrc, bufA, N);
    agg_kernel<128, true><<<(N + 7) / 8, 256, 0, stream>>>(bufA, cursor, csr, ndst, b1, bufB, N);
    // Layer 2
    gemm_mfma_kernel<128><<<gblocks, 256, 0, stream>>>(bufB, W2h, W2l, nsrc, bufA, N);
    agg_kernel<128, true><<<(N + 7) / 8, 256, 0, stream>>>(bufA, cursor, csr, ndst, b2, bufB, N);
    // Layer 3 (no relu): re-zero dummy row for 64-wide layout, then into d_out
    hipMemsetAsync(bufA + (size_t)N * 64, 0, 64 * 4, stream);
    gemm_mfma_kernel<64><<<gblocks, 256, 0, stream>>>(bufB, W3h, W3l, nsrc, bufA, N);
    agg_kernel<64, false><<<(N + 15) / 16, 256, 0, stream>>>(bufA, cursor, csr, ndst, b3, (float*)d_out, N);
}

// Round 6
// 301.765 us; speedup vs baseline: 1.3436x; 1.1550x over previous
//
#include <hip/hip_runtime.h>
#include <math.h>

#define N_NODES 50000
#define K_DIM 128
#define CAP 64   // padded-CSR capacity; in-degree is Poisson(16), P(>=64) ~ e^-40

typedef __attribute__((ext_vector_type(8))) short short8_t;      // 8 bf16 (4 VGPRs)
typedef __attribute__((ext_vector_type(4))) float f32x4_t;       // MFMA acc
typedef __attribute__((ext_vector_type(8))) _Float16 half8_t;    // 8 fp16 (16B)

__device__ inline unsigned short f2bf(float x) {   // round-to-nearest-even
    unsigned u = __float_as_uint(x);
    unsigned r = u + 0x7fffu + ((u >> 16) & 1u);
    return (unsigned short)(r >> 16);
}
__device__ inline float bf2f(unsigned short h) {
    return __uint_as_float(((unsigned)h) << 16);
}

// ---------------- graph build (single fused pass) ----------------

__global__ void build_kernel(const int* __restrict__ src, const int* __restrict__ dst,
                             int E, int* __restrict__ outd, int* __restrict__ cursor,
                             int* __restrict__ csr) {
    int i = blockIdx.x * blockDim.x + threadIdx.x;
    if (i < E) {
        int s = src[i];
        int v = dst[i];
        atomicAdd(&outd[s], 1);
        int p = atomicAdd(&cursor[v], 1);
        if (p < CAP) csr[v * CAP + p] = s;
    }
}

__global__ void norm_kernel(const int* __restrict__ outd, const int* __restrict__ ind,
                            float* __restrict__ nsrc, float* __restrict__ ndst, int n) {
    int i = blockIdx.x * blockDim.x + threadIdx.x;
    if (i < n) {
        int od = outd[i]; if (od < 1) od = 1;
        int id = ind[i];  if (id < 1) id = 1;
        nsrc[i] = 1.0f / sqrtf((float)od);
        ndst[i] = 1.0f / sqrtf((float)id);
    }
}

// ---------------- W split into MFMA B-fragment-major tables ----------------
// WB[tile c][kc][lane][j]: W[k][n], k = kc*32+(lane>>4)*8+j, n = c*16+(lane&15).
__global__ void split_w_frag_kernel(const float* __restrict__ W,
                                    unsigned short* __restrict__ WBh,
                                    unsigned short* __restrict__ WBl, int M) {
    int i = blockIdx.x * blockDim.x + threadIdx.x;   // over (M/16)*4*64
    int total = (M / 16) * 4 * 64;
    if (i >= total) return;
    int c    = i >> 8;
    int rem  = i & 255;
    int kc   = rem >> 6;
    int lane = rem & 63;
    int m = lane & 15, q = lane >> 4;
    int n = c * 16 + m;
    #pragma unroll
    for (int j = 0; j < 8; ++j) {
        int k = kc * 32 + q * 8 + j;
        float w = W[(size_t)k * M + n];
        unsigned short hi = f2bf(w);
        unsigned short lo = f2bf(w - bf2f(hi));
        WBh[(size_t)i * 8 + j] = hi;
        WBl[(size_t)i * 8 + j] = lo;
    }
}

// ---------------- split-bf16 MFMA GEMM, fp16 output ----------------
// Yh[r][c] = (fp16) nsrc[r] * sum_k X[r][k]*W[k][c], K=128. X fp32 -> LDS bf16 hi/lo.
template <int M>
__global__ __launch_bounds__(256) void gemm_mfma_kernel(
        const float* __restrict__ X,
        const unsigned short* __restrict__ WBh_,
        const unsigned short* __restrict__ WBl_,
        const float* __restrict__ nsrc, _Float16* __restrict__ Yh, int n) {
    constexpr int LSTR = 136;   // bf16 row stride: 272B -> 2-way bank alias only (free)
    __shared__ short Xhi[64 * LSTR];
    __shared__ short Xlo[64 * LSTR];
    int tid = threadIdx.x;
    int lane = tid & 63, wave = tid >> 6;
    int rowBlock = blockIdx.x * 64;

    #pragma unroll
    for (int l = 0; l < 8; ++l) {
        int idx = (tid + l * 256) * 4;
        int r = idx >> 7;
        int c = idx & 127;
        float4 v = make_float4(0.f, 0.f, 0.f, 0.f);
        int gr = rowBlock + r;
        if (gr < n) v = *(const float4*)&X[(size_t)gr * K_DIM + c];
        unsigned short h0 = f2bf(v.x), h1 = f2bf(v.y), h2 = f2bf(v.z), h3 = f2bf(v.w);
        short4 hs = {(short)h0, (short)h1, (short)h2, (short)h3};
        short4 ls = {(short)f2bf(v.x - bf2f(h0)), (short)f2bf(v.y - bf2f(h1)),
                     (short)f2bf(v.z - bf2f(h2)), (short)f2bf(v.w - bf2f(h3))};
        *(short4*)&Xhi[r * LSTR + c] = hs;
        *(short4*)&Xlo[r * LSTR + c] = ls;
    }
    __syncthreads();

    int m = lane & 15, q = lane >> 4;
    short8_t ah[4], al[4];
    {
        int abase = (wave * 16 + m) * LSTR + q * 8;
        #pragma unroll
        for (int kc = 0; kc < 4; ++kc) {
            ah[kc] = *(const short8_t*)&Xhi[abase + kc * 32];
            al[kc] = *(const short8_t*)&Xlo[abase + kc * 32];
        }
    }
    float ns[4];
    int orow0 = rowBlock + wave * 16 + q * 4;
    #pragma unroll
    for (int r = 0; r < 4; ++r) ns[r] = (orow0 + r < n) ? nsrc[orow0 + r] : 0.f;

    const short8_t* WBh = (const short8_t*)WBh_;
    const short8_t* WBl = (const short8_t*)WBl_;
    constexpr int CT = M / 16;
    #pragma unroll
    for (int c = 0; c < CT; ++c) {
        short8_t bh[4], bl[4];
        #pragma unroll
        for (int kc = 0; kc < 4; ++kc) {
            bh[kc] = WBh[(c * 4 + kc) * 64 + lane];   // contiguous 1KB per wave
            bl[kc] = WBl[(c * 4 + kc) * 64 + lane];
        }
        f32x4_t acc = {0.f, 0.f, 0.f, 0.f};
        #pragma unroll
        for (int kc = 0; kc < 4; ++kc) {
            acc = __builtin_amdgcn_mfma_f32_16x16x32_bf16(ah[kc], bh[kc], acc, 0, 0, 0);
            acc = __builtin_amdgcn_mfma_f32_16x16x32_bf16(ah[kc], bl[kc], acc, 0, 0, 0);
            acc = __builtin_amdgcn_mfma_f32_16x16x32_bf16(al[kc], bh[kc], acc, 0, 0, 0);
        }
        int col = c * 16 + m;
        #pragma unroll
        for (int r = 0; r < 4; ++r) {
            int row = orow0 + r;
            if (row < n) Yh[(size_t)row * M + col] = (_Float16)(acc[r] * ns[r]);
        }
    }
}

// ---------------- aggregation (fp16 gather, fp32 accumulate) ----------------
// Z[v][f] = act( ndst[v] * sum_{s in padded-CSR[v]} Yh[s][f] + bias[f] )
// M/8 lanes per node; each lane gathers 8 halves (16B) per source.
template <int M, bool RELU>
__global__ __launch_bounds__(256) void agg_kernel(const _Float16* __restrict__ Y,
                                                  const int* __restrict__ indeg,
                                                  const int* __restrict__ csr,
                                                  const float* __restrict__ ndst,
                                                  const float* __restrict__ bias,
                                                  float* __restrict__ Z, int n) {
    constexpr int LPN = M / 8;        // lanes per node (16 for M=128, 8 for M=64)
    constexpr int NPB = 256 / LPN;
    int v = blockIdx.x * NPB + threadIdx.x / LPN;
    if (v >= n) return;
    int f8 = (threadIdx.x % LPN) * 8;
    int deg = indeg[v]; if (deg > CAP) deg = CAP;
    const int* __restrict__ row = &csr[(size_t)v * CAP];
    float acc[8] = {};
    for (int i = 0; i < deg; i += 4) {
        int4 ss = *(const int4*)&row[i];
        int s0 = ss.x;
        int s1 = (i + 1 < deg) ? ss.y : N_NODES;
        int s2 = (i + 2 < deg) ? ss.z : N_NODES;
        int s3 = (i + 3 < deg) ? ss.w : N_NODES;
        half8_t a = *(const half8_t*)&Y[(size_t)s0 * M + f8];
        half8_t b = *(const half8_t*)&Y[(size_t)s1 * M + f8];
        half8_t c = *(const half8_t*)&Y[(size_t)s2 * M + f8];
        half8_t d = *(const half8_t*)&Y[(size_t)s3 * M + f8];
        #pragma unroll
        for (int j = 0; j < 8; ++j)
            acc[j] += ((float)a[j] + (float)b[j]) + ((float)c[j] + (float)d[j]);
    }
    float nd = ndst[v];
    float4 bb0 = *(const float4*)&bias[f8];
    float4 bb1 = *(const float4*)&bias[f8 + 4];
    float o[8];
    o[0] = nd * acc[0] + bb0.x; o[1] = nd * acc[1] + bb0.y;
    o[2] = nd * acc[2] + bb0.z; o[3] = nd * acc[3] + bb0.w;
    o[4] = nd * acc[4] + bb1.x; o[5] = nd * acc[5] + bb1.y;
    o[6] = nd * acc[6] + bb1.z; o[7] = nd * acc[7] + bb1.w;
    if (RELU) {
        #pragma unroll
        for (int j = 0; j < 8; ++j) o[j] = fmaxf(o[j], 0.f);
    }
    *(float4*)&Z[(size_t)v * M + f8]     = make_float4(o[0], o[1], o[2], o[3]);
    *(float4*)&Z[(size_t)v * M + f8 + 4] = make_float4(o[4], o[5], o[6], o[7]);
}

// ---------------- launch ----------------

extern "C" void kernel_launch(void* const* d_in, const int* in_sizes, int n_in,
                              void* d_out, int out_size, void* d_ws, size_t ws_size,
                              hipStream_t stream) {
    const float* features = (const float*)d_in[0];
    const float* W1 = (const float*)d_in[1];
    const float* b1 = (const float*)d_in[2];
    const float* W2 = (const float*)d_in[3];
    const float* b2 = (const float*)d_in[4];
    const float* W3 = (const float*)d_in[5];
    const float* b3 = (const float*)d_in[6];
    const int* src = (const int*)d_in[7];
    const int* dst = (const int*)d_in[8];
    const int E = in_sizes[7];
    const int N = N_NODES;

    char* w = (char*)d_ws;
    auto alloc = [&](size_t bytes) {
        char* p = w;
        w += (bytes + 255) & ~(size_t)255;
        return p;
    };
    _Float16* Yh  = (_Float16*)alloc((size_t)(N + 1) * 128 * 2);  // +dummy row N (zeros)
    float* Zbuf   = (float*)alloc((size_t)N * 128 * 4);
    int*   outd   = (int*)alloc((size_t)N * 4);
    int*   cursor = (int*)alloc((size_t)N * 4);   // becomes in-degree
    float* nsrc   = (float*)alloc((size_t)N * 4);
    float* ndst   = (float*)alloc((size_t)N * 4);
    int*   csr    = (int*)alloc((size_t)N * CAP * 4);
    unsigned short* W1h = (unsigned short*)alloc(128 * 128 * 2);
    unsigned short* W1l = (unsigned short*)alloc(128 * 128 * 2);
    unsigned short* W2h = (unsigned short*)alloc(128 * 128 * 2);
    unsigned short* W2l = (unsigned short*)alloc(128 * 128 * 2);
    unsigned short* W3h = (unsigned short*)alloc(64 * 128 * 2);
    unsigned short* W3l = (unsigned short*)alloc(64 * 128 * 2);

    hipMemsetAsync(outd, 0, (size_t)N * 4, stream);
    hipMemsetAsync(cursor, 0, (size_t)N * 4, stream);
    hipMemsetAsync(Yh + (size_t)N * 128, 0, 128 * 2, stream);  // dummy row (M=128)

    build_kernel<<<(E + 255) / 256, 256, 0, stream>>>(src, dst, E, outd, cursor, csr);
    norm_kernel<<<(N + 255) / 256, 256, 0, stream>>>(outd, cursor, nsrc, ndst, N);
    split_w_frag_kernel<<<8, 256, 0, stream>>>(W1, W1h, W1l, 128);
    split_w_frag_kernel<<<8, 256, 0, stream>>>(W2, W2h, W2l, 128);
    split_w_frag_kernel<<<4, 256, 0, stream>>>(W3, W3h, W3l, 64);

    int gblocks = (N + 63) / 64;
    // Layer 1
    gemm_mfma_kernel<128><<<gblocks, 256, 0, stream>>>(features, W1h, W1l, nsrc, Yh, N);
    agg_kernel<128, true><<<(N + 15) / 16, 256, 0, stream>>>(Yh, cursor, csr, ndst, b1, Zbuf, N);
    // Layer 2
    gemm_mfma_kernel<128><<<gblocks, 256, 0, stream>>>(Zbuf, W2h, W2l, nsrc, Yh, N);
    agg_kernel<128, true><<<(N + 15) / 16, 256, 0, stream>>>(Yh, cursor, csr, ndst, b2, Zbuf, N);
    // Layer 3 (no relu): 64-wide; re-zero dummy row for 64-wide layout
    hipMemsetAsync(Yh + (size_t)N * 64, 0, 64 * 2, stream);
    gemm_mfma_kernel<64><<<gblocks, 256, 0, stream>>>(Zbuf, W3h, W3l, nsrc, Yh, N);
    agg_kernel<64, false><<<(N + 31) / 32, 256, 0, stream>>>(Yh, cursor, csr, ndst, b3, (float*)d_out, N);
}